// Round 5
// baseline (452.694 us; speedup 1.0000x reference)
//
#include <hip/hip_runtime.h>

// ---------------------------------------------------------------------------
// UltimateV7 r5: r3-structure main + lgkm-only barriers + setprio, and a
// single-wave barrier-free select kernel.
// r5 vs r3/r4: (a) main reverted to r3 geometry (16 frag groups, 34.3KB LDS,
// 4 blocks/CU) -- best measured; (b) its 4 stage barriers become raw
// s_barrier with lgkmcnt(0) only (no vmcnt drain -> weight prefetch loads
// can span barriers); (c) s_setprio(1) around MFMA clusters; (d) uv6_select
// rewritten: 64 threads, 0 __syncthreads, shfl-broadcast dot products.
// ---------------------------------------------------------------------------

typedef __attribute__((ext_vector_type(8))) short s16x8;
typedef __attribute__((ext_vector_type(4))) float f32x4;
typedef __attribute__((ext_vector_type(2))) unsigned u32x2;
typedef unsigned short ushort_t;

#define BATCH 131072
#define TBROWS 32
#define HSTR 132        // h row stride (floats): %4==0 aligned b128
#define FGSTR 544       // frag group stride (u16)
#define FQSTR 136       // frag k-quad stride (u16): 68 u32 -> qq spreads banks

// ws layout (bytes)
#define WS_IDX 0        // int[8]
#define WS_PRM 64       // float[8][384]: c1'[256] c2'[128]
#define WS_PB  12352    // float[128]: proj_b + pos
#define WS_PW  12864    // ushort[4096]: proj_w frag-packed bf16
#define WS_W1  21056    // ushort[8][32768]  w1' = ln_s-folded
#define WS_W2  545344   // ushort[8][32768]  w2' = 0.5(1+te)-folded
#define WS_DMP 1069632  // float[16] warm-kernel dump

// lgkm-only barrier: LDS ordering without draining global (vmcnt) loads.
// sched_barrier(0) pins codegen (guide m214 r263/r282 hoist hazard).
#define BARRIER_LDS() do {                                   \
    asm volatile("s_waitcnt lgkmcnt(0)" ::: "memory");       \
    __builtin_amdgcn_s_barrier();                            \
    __builtin_amdgcn_sched_barrier(0);                       \
  } while (0)

__device__ inline ushort_t f2bf(float f) {         // RNE (cold paths)
  unsigned u = __float_as_uint(f);
  u += 0x7fffu + ((u >> 16) & 1u);
  return (ushort_t)(u >> 16);
}
__device__ inline unsigned f2bf2(float lo, float hi) {  // 2 vals -> 1 u32
  unsigned a = __float_as_uint(lo) + 0x8000u;
  unsigned b = __float_as_uint(hi) + 0x8000u;
  return __builtin_amdgcn_perm(b, a, 0x07060302u);  // [b.hi16 : a.hi16]
}

// DPP cross-lane adds within quads (VALU pipe; keeps reductions off DS pipe)
__device__ inline float dpp_xor1(float v) {        // lane ^ 1
  return __int_as_float(__builtin_amdgcn_update_dpp(
      0, __float_as_int(v), 0xB1 /*quad_perm(1,0,3,2)*/, 0xF, 0xF, true));
}
__device__ inline float dpp_xor2(float v) {        // lane ^ 2
  return __int_as_float(__builtin_amdgcn_update_dpp(
      0, __float_as_int(v), 0x4E /*quad_perm(2,3,0,1)*/, 0xF, 0xF, true));
}

// gelu ~= x * sigmoid(1.702 x)
__device__ inline float geluf(float v) {
  float e = __builtin_amdgcn_exp2f(-2.4554670f * v);
  return v * __builtin_amdgcn_rcpf(1.0f + e);
}

// ---------------------------------------------------------------------------
// Kernel 0: warm w1/w2 (8.4 MB) into L2/L3 so the serial select kernel's
// weight streams hit cache, not cold HBM.
// ---------------------------------------------------------------------------
__global__ __launch_bounds__(256) void uv6_warm(
    const float* __restrict__ w1, const float* __restrict__ w2,
    float* __restrict__ dump) {
  int gid = blockIdx.x * 256 + threadIdx.x;      // 131072 threads
  const float4* a = (const float4*)w1;           // 262144 float4
  const float4* b = (const float4*)w2;
  float s = 0.0f;
#pragma unroll
  for (int i = 0; i < 2; ++i) {
    float4 v = a[gid + i * 131072];
    float4 u = b[gid + i * 131072];
    s += v.x + v.y + v.z + v.w + u.x + u.y + u.z + u.w;
  }
  if (s > 1e30f) dump[0] = s;  // never true for these inputs; keeps loads live
}

// ---------------------------------------------------------------------------
// Kernel A (r5): row-0 trajectory on ONE wave, zero barriers. h0 lives as
// 2 floats/lane; all reductions via shfl_xor; matmuls as shfl-broadcast dot
// products with coalesced weight loads (L2-warmed). Exact fp32 (erff),
// same formulas as the previous select (same drift profile).
// ---------------------------------------------------------------------------
__global__ __launch_bounds__(64) void uv6_select(
    const float* __restrict__ x, const float* __restrict__ proj_w,
    const float* __restrict__ proj_b, const float* __restrict__ pos,
    const float* __restrict__ sel_w, const float* __restrict__ sel_b,
    const float* __restrict__ ln_s, const float* __restrict__ ln_b,
    const float* __restrict__ w1, const float* __restrict__ b1,
    const float* __restrict__ w2, const float* __restrict__ b2,
    const float* __restrict__ gate, const float* __restrict__ tf,
    int* __restrict__ wsI) {
  const int lane = threadIdx.x;

  // ---- projection: h0[d] for d = lane, lane+64 ----
  float xv = x[lane & 31];
  float ha = proj_b[lane] + pos[lane];
  float hb = proj_b[lane + 64] + pos[lane + 64];
#pragma unroll
  for (int f = 0; f < 32; ++f) {
    float xf = __shfl(xv, f);
    ha = fmaf(xf, proj_w[f * 128 + lane], ha);
    hb = fmaf(xf, proj_w[f * 128 + lane + 64], hb);
  }

  for (int l = 0; l < 4; ++l) {
    // ---- selector scores (8 outputs, full-wave reduce) ----
    float sc[8];
#pragma unroll
    for (int n = 0; n < 8; ++n) {
      sc[n] = fmaf(ha, sel_w[(l * 128 + lane) * 8 + n],
                   hb * sel_w[(l * 128 + lane + 64) * 8 + n]);
    }
#pragma unroll
    for (int n = 0; n < 8; ++n) {
      sc[n] += __shfl_xor(sc[n], 1);
      sc[n] += __shfl_xor(sc[n], 2);
      sc[n] += __shfl_xor(sc[n], 4);
      sc[n] += __shfl_xor(sc[n], 8);
      sc[n] += __shfl_xor(sc[n], 16);
      sc[n] += __shfl_xor(sc[n], 32);
    }
    float adj[8];
#pragma unroll
    for (int n = 0; n < 8; ++n) {
      float s = 1.0f / (1.0f + __expf(-(sc[n] + sel_b[l * 8 + n])));
      adj[n] = s * 0.6f + 0.2f;   // priority 0.5 * 0.4
    }
    // top-2, replicated in every lane (no divergence)
    int i0 = 0; float v0 = adj[0];
#pragma unroll
    for (int j = 1; j < 8; ++j) if (adj[j] > v0) { v0 = adj[j]; i0 = j; }
    int i1 = -1; float v1 = -1e30f;
#pragma unroll
    for (int j = 0; j < 8; ++j) if (j != i0 && adj[j] > v1) { v1 = adj[j]; i1 = j; }
    if (lane == 0) { wsI[2 * l] = i0; wsI[2 * l + 1] = i1; }

    // ---- run the two selected blocks on row 0 ----
#pragma unroll 1
    for (int kk = 0; kk < 2; ++kk) {
      const int base = l * 8 + (kk == 0 ? i0 : i1);
      // LayerNorm
      float s2 = ha + hb, q2 = ha * ha + hb * hb;
      s2 += __shfl_xor(s2, 1);  q2 += __shfl_xor(q2, 1);
      s2 += __shfl_xor(s2, 2);  q2 += __shfl_xor(q2, 2);
      s2 += __shfl_xor(s2, 4);  q2 += __shfl_xor(q2, 4);
      s2 += __shfl_xor(s2, 8);  q2 += __shfl_xor(q2, 8);
      s2 += __shfl_xor(s2, 16); q2 += __shfl_xor(q2, 16);
      s2 += __shfl_xor(s2, 32); q2 += __shfl_xor(q2, 32);
      float mu = s2 * (1.0f / 128.0f);
      float rstd = rsqrtf(q2 * (1.0f / 128.0f) - mu * mu + 1e-5f);
      float na = (ha - mu) * rstd * ln_s[base * 128 + lane] + ln_b[base * 128 + lane];
      float nb = (hb - mu) * rstd * ln_s[base * 128 + lane + 64] + ln_b[base * 128 + lane + 64];

      // mm1: z1[n] for n = lane + 64*jj
      float z[4];
#pragma unroll
      for (int jj = 0; jj < 4; ++jj) z[jj] = b1[base * 256 + 64 * jj + lane];
      const float* W1 = w1 + base * 32768;
#pragma unroll 8
      for (int d = 0; d < 64; ++d) {
        float u = __shfl(na, d);
#pragma unroll
        for (int jj = 0; jj < 4; ++jj)
          z[jj] = fmaf(u, W1[d * 256 + 64 * jj + lane], z[jj]);
      }
#pragma unroll 8
      for (int d = 0; d < 64; ++d) {
        float u = __shfl(nb, d);
#pragma unroll
        for (int jj = 0; jj < 4; ++jj)
          z[jj] = fmaf(u, W1[(64 + d) * 256 + 64 * jj + lane], z[jj]);
      }
      // exact gelu
#pragma unroll
      for (int jj = 0; jj < 4; ++jj)
        z[jj] = z[jj] * 0.5f * (1.0f + erff(z[jj] * 0.70710678118f));

      // mm2: z2[d] for d = lane, lane+64
      float s0 = 0.0f, s1 = 0.0f;
      const float* W2 = w2 + base * 32768;
#pragma unroll
      for (int jj = 0; jj < 4; ++jj) {
#pragma unroll 8
        for (int k = 0; k < 64; ++k) {
          float u = __shfl(z[jj], k);
          s0 = fmaf(u, W2[(jj * 64 + k) * 128 + lane], s0);
          s1 = fmaf(u, W2[(jj * 64 + k) * 128 + lane + 64], s1);
        }
      }
      s0 += b2[base * 128 + lane];
      s1 += b2[base * 128 + lane + 64];
      float te0 = tf[lane] * (1.0f / (1.0f + __expf(-gate[base * 128 + lane])));
      float te1 = tf[lane + 64] * (1.0f / (1.0f + __expf(-gate[base * 128 + lane + 64])));
      ha += 0.5f * s0 * (1.0f + te0);
      hb += 0.5f * s1 * (1.0f + te1);
    }
  }
}

// ---------------------------------------------------------------------------
// Kernel P (r3): blocks 0..15 pack w1'/w2' via LDS transpose tile --
// coalesced n-inner float4 reads, bf16 scatter into frag layout in LDS,
// coalesced uint4 writes out. Blocks 16..23 compute c1' = b1 + ln_b@w1 and
// c2' = 0.5(1+te).b2; blocks 24..40 pack proj fragments + pb.
// Frag positions (must match main's reads):
//   w1: p1(k,n) = (n>>4)*2048 + (k>>5)*512 + ((k>>3)&3)*128 + (n&15)*8 + (k&7)
//   w2: p2(k,n) = (n>>4)*4096 + (k>>5)*512 + ((k>>3)&3)*128 + (n&15)*8 + (k&7)
// ---------------------------------------------------------------------------
__global__ __launch_bounds__(256) void uv6_pack(
    const float* __restrict__ w1, const float* __restrict__ w2,
    const float* __restrict__ ln_s, const float* __restrict__ ln_b,
    const float* __restrict__ b1, const float* __restrict__ b2,
    const float* __restrict__ gate, const float* __restrict__ tf,
    const float* __restrict__ proj_w, const float* __restrict__ proj_b,
    const float* __restrict__ pos, const int* __restrict__ wsI,
    ushort_t* __restrict__ w1P, ushort_t* __restrict__ w2P,
    float* __restrict__ wsP, ushort_t* __restrict__ pwP,
    float* __restrict__ pb) {
  const int bx = blockIdx.x;
  const int t = threadIdx.x;
  if (bx < 16) {
    __shared__ ushort_t tile[32768];   // 64 KB
    int s = bx >> 1;
    int base = (s >> 1) * 8 + wsI[s];
    if ((bx & 1) == 0) {
      // ---- w1' = ln_s-folded: 128k x 256n ----
      const float* W = w1 + base * 32768;
      const float* LS = ln_s + base * 128;
      int kk = t >> 6, n4 = (t & 63) * 4;
#pragma unroll
      for (int it = 0; it < 16; ++it) {
        int k = it * 8 + kk * 2;
        float4 v0 = *(const float4*)(W + k * 256 + n4);
        float4 v1 = *(const float4*)(W + (k + 1) * 256 + n4);
        float s0 = LS[k], s1 = LS[k + 1];
        int pk = (k >> 5) * 512 + ((k >> 3) & 3) * 128 + (k & 7);
        const float* e0 = (const float*)&v0;
        const float* e1 = (const float*)&v1;
#pragma unroll
        for (int i = 0; i < 4; ++i) {
          int n = n4 + i;
          int pos_ = (n >> 4) * 2048 + pk + (n & 15) * 8;
          *(unsigned*)&tile[pos_] =
              (unsigned)f2bf(e0[i] * s0) | ((unsigned)f2bf(e1[i] * s1) << 16);
        }
      }
      __syncthreads();
      ushort_t* dst = w1P + s * 32768;
#pragma unroll
      for (int it = 0; it < 16; ++it)
        *(uint4*)(dst + (it * 256 + t) * 8) = *(const uint4*)(tile + (it * 256 + t) * 8);
    } else {
      // ---- w2' = 0.5(1+te)-folded: 256k x 128n ----
      const float* W = w2 + base * 32768;
      int kk = t >> 5, n4 = (t & 31) * 4;
      float te4[4];
#pragma unroll
      for (int i = 0; i < 4; ++i)
        te4[i] = 0.5f * (1.0f + tf[n4 + i] *
                 (1.0f / (1.0f + __expf(-gate[base * 128 + n4 + i]))));
#pragma unroll
      for (int it = 0; it < 16; ++it) {
        int k = it * 16 + kk * 2;
        float4 v0 = *(const float4*)(W + k * 128 + n4);
        float4 v1 = *(const float4*)(W + (k + 1) * 128 + n4);
        int pk = (k >> 5) * 512 + ((k >> 3) & 3) * 128 + (k & 7);
        const float* e0 = (const float*)&v0;
        const float* e1 = (const float*)&v1;
#pragma unroll
        for (int i = 0; i < 4; ++i) {
          int n = n4 + i;
          int pos_ = (n >> 4) * 4096 + pk + (n & 15) * 8;
          *(unsigned*)&tile[pos_] =
              (unsigned)f2bf(e0[i] * te4[i]) | ((unsigned)f2bf(e1[i] * te4[i]) << 16);
        }
      }
      __syncthreads();
      ushort_t* dst = w2P + s * 32768;
#pragma unroll
      for (int it = 0; it < 16; ++it)
        *(uint4*)(dst + (it * 256 + t) * 8) = *(const uint4*)(tile + (it * 256 + t) * 8);
    }
    return;
  }
  if (bx < 24) {
    int s = bx - 16, n = t;
    int base = (s >> 1) * 8 + wsI[s];
    float a = b1[base * 256 + n];
#pragma unroll 16
    for (int k = 0; k < 128; ++k)
      a += ln_b[base * 128 + k] * w1[(base * 128 + k) * 256 + n];
    wsP[s * 384 + n] = a;
    if (n < 128) {
      float te = tf[n] * (1.0f / (1.0f + __expf(-gate[base * 128 + n])));
      wsP[s * 384 + 256 + n] = 0.5f * (1.0f + te) * b2[base * 128 + n];
    }
    return;
  }
  int gid = (bx - 24) * 256 + t;
  if (gid < 4096) {
    int j = gid & 7, ln = (gid >> 3) & 63, nt = gid >> 9;
    int k = (ln >> 4) * 8 + j, n = nt * 16 + (ln & 15);
    pwP[gid] = f2bf(proj_w[k * 128 + n]);
  } else if (gid < 4224) {
    int d = gid - 4096;
    pb[d] = proj_b[d] + pos[d];
  }
}

// ---------------------------------------------------------------------------
// Kernel B: the batch. 4096 blocks x 256 thr (4 waves), 32 rows/block,
// 4 blocks/CU (LDS 34.3KB, r3 geometry). mm1 SWAPPED (z1^T = mfma(w1frag,
// hnfrag)) -> gelu scatter = 8 conflict-free ds_write_b64/wave.
// r5: stage barriers are lgkm-only raw s_barrier (global weight prefetch
// loads stay in flight across barriers); s_setprio(1) around MFMA clusters.
// Frag LDS groups (16): g = rt*8 + kb, element (kq,m,j) at
// g*544 + kq*136 + m*8 + j  (hn uses kb 0..3; z1 uses kb 0..7, phase-union).
// ---------------------------------------------------------------------------
__global__ __launch_bounds__(256, 4) void uv6_main(
    const float* __restrict__ x, const float* __restrict__ cls_w,
    const float* __restrict__ cls_b, const float* __restrict__ wsP,
    const float* __restrict__ pb, const ushort_t* __restrict__ pwP,
    const ushort_t* __restrict__ w1P, const ushort_t* __restrict__ w2P,
    float* __restrict__ out) {
  __shared__ float hbuf[TBROWS * HSTR];      // 16896 B
  __shared__ ushort_t frag[16 * FGSTR];      // 17408 B (x/hn/z1 phase-unioned)

  const int tid = threadIdx.x;
  const int w = tid >> 6, lane = tid & 63, q = lane >> 4, m0 = lane & 15;
  const int r = tid >> 3, p = tid & 7;       // LN/logits row (0..31) / col-part
  const int rt_r = r >> 4, m_r = r & 15;
  const long rowbase = (long)blockIdx.x * TBROWS;
  ushort_t* fb = &frag[q * FQSTR + m0 * 8];  // per-lane frag base (mm reads)

  // ---- phase 0: x tile [32 x 32] -> A-fragments (bf16) ----
  {
    float4 xv = *(const float4*)(x + (rowbase + r) * 32 + p * 4);
    unsigned u01 = f2bf2(xv.x, xv.y), u23 = f2bf2(xv.z, xv.w);
    ushort_t* dst = &frag[(rt_r * 8) * FGSTR + (p >> 1) * FQSTR + m_r * 8 + (p & 1) * 4];
    *(unsigned*)dst = u01;
    *(unsigned*)(dst + 2) = u23;
  }
  __syncthreads();

  // ---- projection: h = x @ proj_w + (proj_b+pos) ; wave w owns nt {2w,2w+1}
  {
    s16x8 bp0 = *(const s16x8*)(pwP + ((2 * w + 0) * 64 + lane) * 8);
    s16x8 bp1 = *(const s16x8*)(pwP + ((2 * w + 1) * 64 + lane) * 8);
    float bv0 = pb[(2 * w + 0) * 16 + m0];
    float bv1 = pb[(2 * w + 1) * 16 + m0];
    f32x4 acc[2][2];
#pragma unroll
    for (int rt = 0; rt < 2; ++rt) {
      acc[rt][0] = (f32x4){bv0, bv0, bv0, bv0};
      acc[rt][1] = (f32x4){bv1, bv1, bv1, bv1};
    }
#pragma unroll
    for (int rt = 0; rt < 2; ++rt) {
      s16x8 af = *(const s16x8*)&fb[(rt * 8) * FGSTR];
      acc[rt][0] = __builtin_amdgcn_mfma_f32_16x16x32_bf16(af, bp0, acc[rt][0], 0, 0, 0);
      acc[rt][1] = __builtin_amdgcn_mfma_f32_16x16x32_bf16(af, bp1, acc[rt][1], 0, 0, 0);
    }
#pragma unroll
    for (int rt = 0; rt < 2; ++rt)
#pragma unroll
      for (int ni = 0; ni < 2; ++ni) {
        int col = (2 * w + ni) * 16 + m0;
#pragma unroll
        for (int reg = 0; reg < 4; ++reg)
          hbuf[(rt * 16 + 4 * q + reg) * HSTR + col] = acc[rt][ni][reg];
      }
  }
  __syncthreads();

  float* outH = out + (size_t)BATCH * 2;

  // ---- 8 FFN block stages ----
  for (int s = 0; s < 8; ++s) {
    const float* c1 = wsP + s * 384;
    const float* c2 = c1 + 256;
    const ushort_t* w1s = w1P + s * 32768;
    const ushort_t* w2s = w2P + s * 32768;

    // ---- prefetch mm1 A-frags (hidden behind LN): n-tiles 4w..4w+3 ----
    s16x8 bfr1[4][4];
#pragma unroll
    for (int ni = 0; ni < 4; ++ni)
#pragma unroll
      for (int ks = 0; ks < 4; ++ks)
        bfr1[ni][ks] = *(const s16x8*)(w1s + (((4 * w + ni) * 4 + ks) * 64 + lane) * 8);

    // -- LayerNorm (folded: hn = (h-mu)*rstd) + pack into frag layout --
    {
      const float* hr = hbuf + r * HSTR + p * 16;
      float hv[16];
#pragma unroll
      for (int i = 0; i < 4; ++i)
        *(float4*)(hv + i * 4) = *(const float4*)(hr + i * 4);
      float sum = 0.0f, ssq = 0.0f;
#pragma unroll
      for (int i = 0; i < 16; ++i) { sum += hv[i]; ssq += hv[i] * hv[i]; }
      sum += dpp_xor1(sum); ssq += dpp_xor1(ssq);
      sum += dpp_xor2(sum); ssq += dpp_xor2(ssq);
      sum += __shfl_xor(sum, 4); ssq += __shfl_xor(ssq, 4);
      float mu = sum * (1.0f / 128.0f);
      float rstd = rsqrtf(ssq * (1.0f / 128.0f) - mu * mu + 1e-5f);
      float nmu = -mu * rstd;
#pragma unroll
      for (int g = 0; g < 2; ++g) {
        union { unsigned u[4]; s16x8 v; } tv;
#pragma unroll
        for (int jj = 0; jj < 4; ++jj) {
          float a = fmaf(hv[g * 8 + jj * 2], rstd, nmu);
          float b = fmaf(hv[g * 8 + jj * 2 + 1], rstd, nmu);
          tv.u[jj] = f2bf2(a, b);
        }
        // col c = 16p + 8g + j  ->  kb = p>>1, k-quad = (p&1)*2 + g
        int kb = p >> 1, kq = (p & 1) * 2 + g;
        *(s16x8*)&frag[(rt_r * 8 + kb) * FGSTR + kq * FQSTR + m_r * 8] = tv.v;
      }
    }
    BARRIER_LDS();   // barrier A: hn frags ready

    // -- matmul1 (SWAPPED): z1^T = w1'^T @ hn^T, wave w owns nt {4w..4w+3} --
    f32x4 a1[2][4];
#pragma unroll
    for (int ni = 0; ni < 4; ++ni) {
      f32x4 bv = *(const f32x4*)&c1[(4 * w + ni) * 16 + 4 * q];
#pragma unroll
      for (int rt = 0; rt < 2; ++rt) a1[rt][ni] = bv;
    }
    __builtin_amdgcn_s_setprio(1);
#pragma unroll
    for (int ks = 0; ks < 4; ++ks) {
      s16x8 hf[2];
#pragma unroll
      for (int rt = 0; rt < 2; ++rt)
        hf[rt] = *(const s16x8*)&fb[(rt * 8 + ks) * FGSTR];
#pragma unroll
      for (int rt = 0; rt < 2; ++rt)
#pragma unroll
        for (int ni = 0; ni < 4; ++ni)
          a1[rt][ni] = __builtin_amdgcn_mfma_f32_16x16x32_bf16(bfr1[ni][ks], hf[rt], a1[rt][ni], 0, 0, 0);
    }
    __builtin_amdgcn_s_setprio(0);
    BARRIER_LDS();   // barrier M: all waves done reading hn frags

    // ---- prefetch mm2 B-frags + c2 (hidden behind gelu/scatter) ----
    s16x8 bfr2[2][8];
#pragma unroll
    for (int ni = 0; ni < 2; ++ni)
#pragma unroll
      for (int ks = 0; ks < 8; ++ks)
        bfr2[ni][ks] = *(const s16x8*)(w2s + (((2 * w + ni) * 8 + ks) * 64 + lane) * 8);
    float cv0 = c2[(2 * w + 0) * 16 + m0];
    float cv1 = c2[(2 * w + 1) * 16 + m0];

    // -- gelu + pack z1^T into mm2 A-frag layout: 8 x ds_write_b64 --
    // n = (4w+ni)*16 + 4q + reg -> kb = 2w+(ni>>1), kq = (2ni+(q>>1))&3,
    // j = 4(q&1)+reg  (4 consecutive j per lane -> one b64)
    {
      int j0 = 4 * (q & 1), kqb = q >> 1;
#pragma unroll
      for (int ni = 0; ni < 4; ++ni) {
        int kb = 2 * w + (ni >> 1);
        int kq = (2 * ni + kqb) & 3;
#pragma unroll
        for (int rt = 0; rt < 2; ++rt) {
          unsigned lo = f2bf2(geluf(a1[rt][ni][0]), geluf(a1[rt][ni][1]));
          unsigned hi = f2bf2(geluf(a1[rt][ni][2]), geluf(a1[rt][ni][3]));
          *(u32x2*)&frag[(rt * 8 + kb) * FGSTR + kq * FQSTR + m0 * 8 + j0] =
              (u32x2){lo, hi};
        }
      }
    }
    BARRIER_LDS();   // barrier B: z1 frags ready

    // -- matmul2: z2' = z1 @ w2' + c2' (wave w owns nt2 {2w, 2w+1}) --
    f32x4 a2[2][2];
#pragma unroll
    for (int rt = 0; rt < 2; ++rt) {
      a2[rt][0] = (f32x4){cv0, cv0, cv0, cv0};
      a2[rt][1] = (f32x4){cv1, cv1, cv1, cv1};
    }
    __builtin_amdgcn_s_setprio(1);
#pragma unroll
    for (int kb = 0; kb < 8; ++kb) {
      s16x8 af[2];
#pragma unroll
      for (int rt = 0; rt < 2; ++rt)
        af[rt] = *(const s16x8*)&fb[(rt * 8 + kb) * FGSTR];
#pragma unroll
      for (int rt = 0; rt < 2; ++rt) {
        a2[rt][0] = __builtin_amdgcn_mfma_f32_16x16x32_bf16(af[rt], bfr2[0][kb], a2[rt][0], 0, 0, 0);
        a2[rt][1] = __builtin_amdgcn_mfma_f32_16x16x32_bf16(af[rt], bfr2[1][kb], a2[rt][1], 0, 0, 0);
      }
    }
    __builtin_amdgcn_s_setprio(0);

    // -- epilogue: h += z2' (scaling folded into w2'/c2') --
#pragma unroll
    for (int rt = 0; rt < 2; ++rt)
#pragma unroll
      for (int ni = 0; ni < 2; ++ni) {
        int col = (2 * w + ni) * 16 + m0;
#pragma unroll
        for (int reg = 0; reg < 4; ++reg)
          hbuf[(rt * 16 + 4 * q + reg) * HSTR + col] += a2[rt][ni][reg];
      }
    BARRIER_LDS();   // barrier C: h complete for next LN
  }

  // ---- h write-out: flat, lane-contiguous float4 (coalesced) ----
#pragma unroll
  for (int it = 0; it < 4; ++it) {
    int p4 = it * 256 + tid;
    int row = p4 >> 5, c = (p4 & 31) * 4;
    float4 o = *(const float4*)(hbuf + row * HSTR + c);
    *(float4*)(outH + rowbase * 128 + p4 * 4) = o;
  }

  // ---- logits = h @ cls_w + cls_b (8 lanes/row, DPP+shfl reduce) ----
  {
    const float* hr = hbuf + r * HSTR + p * 16;
    float l0 = 0.0f, l1 = 0.0f;
#pragma unroll
    for (int i = 0; i < 16; i += 4) {
      float4 v = *(const float4*)(hr + i);
      int c = (p * 16 + i) * 2;
      l0 += v.x * cls_w[c] + v.y * cls_w[c + 2] + v.z * cls_w[c + 4] + v.w * cls_w[c + 6];
      l1 += v.x * cls_w[c + 1] + v.y * cls_w[c + 3] + v.z * cls_w[c + 5] + v.w * cls_w[c + 7];
    }
    l0 += dpp_xor1(l0); l1 += dpp_xor1(l1);
    l0 += dpp_xor2(l0); l1 += dpp_xor2(l1);
    l0 += __shfl_xor(l0, 4); l1 += __shfl_xor(l1, 4);
    if (p == 0) {
      float2 lg = {l0 + cls_b[0], l1 + cls_b[1]};
      *(float2*)(out + (rowbase + r) * 2) = lg;
    }
  }
}

// ---------------------------------------------------------------------------
extern "C" void kernel_launch(void* const* d_in, const int* in_sizes, int n_in,
                              void* d_out, int out_size, void* d_ws, size_t ws_size,
                              hipStream_t stream) {
  (void)in_sizes; (void)n_in; (void)out_size; (void)ws_size;
  const float* x      = (const float*)d_in[0];
  const float* proj_w = (const float*)d_in[1];
  const float* proj_b = (const float*)d_in[2];
  const float* pos    = (const float*)d_in[3];
  const float* sel_w  = (const float*)d_in[4];
  const float* sel_b  = (const float*)d_in[5];
  const float* ln_s   = (const float*)d_in[6];
  const float* ln_b   = (const float*)d_in[7];
  const float* w1     = (const float*)d_in[8];
  const float* b1     = (const float*)d_in[9];
  const float* w2     = (const float*)d_in[10];
  const float* b2     = (const float*)d_in[11];
  const float* gate   = (const float*)d_in[12];
  const float* cls_w  = (const float*)d_in[13];
  const float* cls_b  = (const float*)d_in[14];
  const float* tf     = (const float*)d_in[15];

  char* ws = (char*)d_ws;
  int* wsI        = (int*)(ws + WS_IDX);
  float* wsP      = (float*)(ws + WS_PRM);
  float* pb       = (float*)(ws + WS_PB);
  ushort_t* pwP   = (ushort_t*)(ws + WS_PW);
  ushort_t* w1P   = (ushort_t*)(ws + WS_W1);
  ushort_t* w2P   = (ushort_t*)(ws + WS_W2);
  float* dump     = (float*)(ws + WS_DMP);
  float* outF     = (float*)d_out;

  uv6_warm<<<512, 256, 0, stream>>>(w1, w2, dump);
  uv6_select<<<1, 64, 0, stream>>>(x, proj_w, proj_b, pos, sel_w, sel_b, ln_s,
                                   ln_b, w1, b1, w2, b2, gate, tf, wsI);
  uv6_pack<<<41, 256, 0, stream>>>(w1, w2, ln_s, ln_b, b1, b2, gate, tf,
                                   proj_w, proj_b, pos, wsI, w1P, w2P, wsP,
                                   pwP, pb);
  uv6_main<<<BATCH / TBROWS, 256, 0, stream>>>(x, cls_w, cls_b, wsP, pb, pwP,
                                               w1P, w2P, outF);
}

// Round 8
// 362.268 us; speedup vs baseline: 1.2496x; 1.2496x over previous
//
#include <hip/hip_runtime.h>

// ---------------------------------------------------------------------------
// UltimateV7 r8: verified composite. uv6_main = r5's exact kernel (243.5us,
// harness-verified: r3 geometry, 4 blocks/CU, swapped mm1, lgkm-only
// barriers + two-sided fence, setprio); uv6_select = the 1024-thread
// verified version (r0-r4); pack/warm = r3. The r6/r7 h-in-registers
// structure is parked: it races (non-deterministic absmax across identical
// binaries) and two rounds of fence fixes did not localize it.
// ---------------------------------------------------------------------------

typedef __attribute__((ext_vector_type(8))) short s16x8;
typedef __attribute__((ext_vector_type(4))) float f32x4;
typedef __attribute__((ext_vector_type(2))) unsigned u32x2;
typedef unsigned short ushort_t;

#define BATCH 131072
#define TBROWS 32
#define HSTR 132        // h row stride (floats): %4==0 aligned b128
#define FGSTR 544       // frag group stride (u16)
#define FQSTR 136       // frag k-quad stride (u16)

// ws layout (bytes)
#define WS_IDX 0        // int[8]
#define WS_PRM 64       // float[8][384]: c1'[256] c2'[128]
#define WS_PB  12352    // float[128]: proj_b + pos
#define WS_PW  12864    // ushort[4096]: proj_w frag-packed bf16
#define WS_W1  21056    // ushort[8][32768]  w1' = ln_s-folded
#define WS_W2  545344   // ushort[8][32768]  w2' = 0.5(1+te)-folded
#define WS_DMP 1069632  // float[16] warm-kernel dump

// lgkm-only barrier with two-sided compiler memory fence.
#define BARRIER_LDS() do {                                   \
    asm volatile("s_waitcnt lgkmcnt(0)" ::: "memory");       \
    __builtin_amdgcn_s_barrier();                            \
    asm volatile("" ::: "memory");                           \
    __builtin_amdgcn_sched_barrier(0);                       \
  } while (0)

__device__ inline ushort_t f2bf(float f) {         // RNE (cold paths)
  unsigned u = __float_as_uint(f);
  u += 0x7fffu + ((u >> 16) & 1u);
  return (ushort_t)(u >> 16);
}
__device__ inline unsigned f2bf2(float lo, float hi) {  // 2 vals -> 1 u32
  unsigned a = __float_as_uint(lo) + 0x8000u;
  unsigned b = __float_as_uint(hi) + 0x8000u;
  return __builtin_amdgcn_perm(b, a, 0x07060302u);  // [b.hi16 : a.hi16]
}

// DPP cross-lane adds within quads (VALU pipe; keeps reductions off DS pipe)
__device__ inline float dpp_xor1(float v) {        // lane ^ 1
  return __int_as_float(__builtin_amdgcn_update_dpp(
      0, __float_as_int(v), 0xB1 /*quad_perm(1,0,3,2)*/, 0xF, 0xF, true));
}
__device__ inline float dpp_xor2(float v) {        // lane ^ 2
  return __int_as_float(__builtin_amdgcn_update_dpp(
      0, __float_as_int(v), 0x4E /*quad_perm(2,3,0,1)*/, 0xF, 0xF, true));
}

// gelu ~= x * sigmoid(1.702 x)
__device__ inline float geluf(float v) {
  float e = __builtin_amdgcn_exp2f(-2.4554670f * v);
  return v * __builtin_amdgcn_rcpf(1.0f + e);
}

// ---------------------------------------------------------------------------
// Kernel 0: warm w1/w2 (8.4 MB) into L2/L3 for the serial select kernel.
// ---------------------------------------------------------------------------
__global__ __launch_bounds__(256) void uv6_warm(
    const float* __restrict__ w1, const float* __restrict__ w2,
    float* __restrict__ dump) {
  int gid = blockIdx.x * 256 + threadIdx.x;      // 131072 threads
  const float4* a = (const float4*)w1;           // 262144 float4
  const float4* b = (const float4*)w2;
  float s = 0.0f;
#pragma unroll
  for (int i = 0; i < 2; ++i) {
    float4 v = a[gid + i * 131072];
    float4 u = b[gid + i * 131072];
    s += v.x + v.y + v.z + v.w + u.x + u.y + u.z + u.w;
  }
  if (s > 1e30f) dump[0] = s;  // never true; keeps loads live
}

// ---------------------------------------------------------------------------
// Kernel A: row-0 trajectory, exact fp32 (erff). 1024 threads; per selection
// both weight matrices prefetched to registers; shfl-based reductions.
// (Verified r0-r4; the r5 single-wave variant was latency-bound, +90us.)
// ---------------------------------------------------------------------------
__global__ __launch_bounds__(1024) void uv6_select(
    const float* __restrict__ x, const float* __restrict__ proj_w,
    const float* __restrict__ proj_b, const float* __restrict__ pos,
    const float* __restrict__ sel_w, const float* __restrict__ sel_b,
    const float* __restrict__ ln_s, const float* __restrict__ ln_b,
    const float* __restrict__ w1, const float* __restrict__ b1,
    const float* __restrict__ w2, const float* __restrict__ b2,
    const float* __restrict__ gate, const float* __restrict__ tf,
    int* __restrict__ wsI) {
  __shared__ float h0[128], hn[128], z1[256];
  __shared__ float red[1024];
  __shared__ float wred[128];
  __shared__ float adjs[8];
  __shared__ int top[2];
  __shared__ float stat[2];
  const int t = threadIdx.x;
  const int lane = t & 63, wv = t >> 6;
  const int n1 = t & 255, dp1 = t >> 8;   // mm1 ownership
  const int n2 = t & 127, dp2 = t >> 7;   // mm2 ownership

  if (t < 128) {
    float a = proj_b[t] + pos[t];
#pragma unroll
    for (int f = 0; f < 32; ++f) a += x[f] * proj_w[f * 128 + t];
    h0[t] = a;
  }
  __syncthreads();

  for (int l = 0; l < 4; ++l) {
    {
      float pp = h0[t >> 3] * sel_w[(l * 128 + (t >> 3)) * 8 + (t & 7)];
      pp += __shfl_xor(pp, 8);
      pp += __shfl_xor(pp, 16);
      pp += __shfl_xor(pp, 32);
      if (lane < 8) wred[wv * 8 + lane] = pp;
    }
    __syncthreads();
    if (t < 8) {
      float sc = sel_b[l * 8 + t];
#pragma unroll
      for (int v = 0; v < 16; ++v) sc += wred[v * 8 + t];
      sc = 1.0f / (1.0f + __expf(-sc));
      adjs[t] = sc * 0.6f + 0.2f;  // priority 0.5 * 0.4
    }
    __syncthreads();
    if (t == 0) {
      int i0 = 0; float v0 = adjs[0];
      for (int j = 1; j < 8; ++j) if (adjs[j] > v0) { v0 = adjs[j]; i0 = j; }
      int i1 = -1; float v1 = -1e30f;
      for (int j = 0; j < 8; ++j) if (j != i0 && adjs[j] > v1) { v1 = adjs[j]; i1 = j; }
      top[0] = i0; top[1] = i1;
      wsI[2 * l] = i0; wsI[2 * l + 1] = i1;
    }
    __syncthreads();
    for (int kk = 0; kk < 2; ++kk) {
      const int base = l * 8 + top[kk];
      float w1v[32], w2v[32];
      const float* w1p = w1 + (base * 128 + dp1 * 32) * 256 + n1;
      const float* w2p = w2 + (base * 256 + dp2 * 32) * 128 + n2;
#pragma unroll
      for (int j = 0; j < 32; ++j) w1v[j] = w1p[j * 256];
#pragma unroll
      for (int j = 0; j < 32; ++j) w2v[j] = w2p[j * 128];
      if (t < 64) {
        float a = h0[t], b = h0[t + 64];
        float s2 = a + b, q2 = a * a + b * b;
        s2 += __shfl_xor(s2, 1);  q2 += __shfl_xor(q2, 1);
        s2 += __shfl_xor(s2, 2);  q2 += __shfl_xor(q2, 2);
        s2 += __shfl_xor(s2, 4);  q2 += __shfl_xor(q2, 4);
        s2 += __shfl_xor(s2, 8);  q2 += __shfl_xor(q2, 8);
        s2 += __shfl_xor(s2, 16); q2 += __shfl_xor(q2, 16);
        s2 += __shfl_xor(s2, 32); q2 += __shfl_xor(q2, 32);
        if (t == 0) {
          float mu = s2 * (1.0f / 128.0f);
          stat[0] = mu;
          stat[1] = rsqrtf(q2 * (1.0f / 128.0f) - mu * mu + 1e-5f);
        }
      }
      __syncthreads();
      if (t < 128)
        hn[t] = (h0[t] - stat[0]) * stat[1] * ln_s[base * 128 + t] + ln_b[base * 128 + t];
      __syncthreads();
      {
        float a = 0.0f;
#pragma unroll
        for (int j = 0; j < 32; ++j) a += hn[dp1 * 32 + j] * w1v[j];
        red[dp1 * 256 + n1] = a;
      }
      __syncthreads();
      if (t < 256) {
        float z = red[t] + red[256 + t] + red[512 + t] + red[768 + t] + b1[base * 256 + t];
        z1[t] = z * 0.5f * (1.0f + erff(z * 0.70710678118f));  // exact gelu
      }
      __syncthreads();
      {
        float a = 0.0f;
#pragma unroll
        for (int j = 0; j < 32; ++j) a += z1[dp2 * 32 + j] * w2v[j];
        red[dp2 * 128 + n2] = a;
      }
      __syncthreads();
      if (t < 128) {
        float z2 = b2[base * 128 + t];
#pragma unroll
        for (int v = 0; v < 8; ++v) z2 += red[v * 128 + t];
        float te = tf[t] * (1.0f / (1.0f + __expf(-gate[base * 128 + t])));
        h0[t] += 0.5f * z2 * (1.0f + te);
      }
      __syncthreads();
    }
  }
}

// ---------------------------------------------------------------------------
// Kernel P (r3): blocks 0..15 pack w1'/w2' via LDS transpose tile;
// blocks 16..23 compute c1'/c2'; blocks 24..40 pack proj fragments + pb.
//   w1: p1(k,n) = (n>>4)*2048 + (k>>5)*512 + ((k>>3)&3)*128 + (n&15)*8 + (k&7)
//   w2: p2(k,n) = (n>>4)*4096 + (k>>5)*512 + ((k>>3)&3)*128 + (n&15)*8 + (k&7)
// ---------------------------------------------------------------------------
__global__ __launch_bounds__(256) void uv6_pack(
    const float* __restrict__ w1, const float* __restrict__ w2,
    const float* __restrict__ ln_s, const float* __restrict__ ln_b,
    const float* __restrict__ b1, const float* __restrict__ b2,
    const float* __restrict__ gate, const float* __restrict__ tf,
    const float* __restrict__ proj_w, const float* __restrict__ proj_b,
    const float* __restrict__ pos, const int* __restrict__ wsI,
    ushort_t* __restrict__ w1P, ushort_t* __restrict__ w2P,
    float* __restrict__ wsP, ushort_t* __restrict__ pwP,
    float* __restrict__ pb) {
  const int bx = blockIdx.x;
  const int t = threadIdx.x;
  if (bx < 16) {
    __shared__ ushort_t tile[32768];   // 64 KB
    int s = bx >> 1;
    int base = (s >> 1) * 8 + wsI[s];
    if ((bx & 1) == 0) {
      const float* W = w1 + base * 32768;
      const float* LS = ln_s + base * 128;
      int kk = t >> 6, n4 = (t & 63) * 4;
#pragma unroll
      for (int it = 0; it < 16; ++it) {
        int k = it * 8 + kk * 2;
        float4 v0 = *(const float4*)(W + k * 256 + n4);
        float4 v1 = *(const float4*)(W + (k + 1) * 256 + n4);
        float s0 = LS[k], s1 = LS[k + 1];
        int pk = (k >> 5) * 512 + ((k >> 3) & 3) * 128 + (k & 7);
        const float* e0 = (const float*)&v0;
        const float* e1 = (const float*)&v1;
#pragma unroll
        for (int i = 0; i < 4; ++i) {
          int n = n4 + i;
          int pos_ = (n >> 4) * 2048 + pk + (n & 15) * 8;
          *(unsigned*)&tile[pos_] =
              (unsigned)f2bf(e0[i] * s0) | ((unsigned)f2bf(e1[i] * s1) << 16);
        }
      }
      __syncthreads();
      ushort_t* dst = w1P + s * 32768;
#pragma unroll
      for (int it = 0; it < 16; ++it)
        *(uint4*)(dst + (it * 256 + t) * 8) = *(const uint4*)(tile + (it * 256 + t) * 8);
    } else {
      const float* W = w2 + base * 32768;
      int kk = t >> 5, n4 = (t & 31) * 4;
      float te4[4];
#pragma unroll
      for (int i = 0; i < 4; ++i)
        te4[i] = 0.5f * (1.0f + tf[n4 + i] *
                 (1.0f / (1.0f + __expf(-gate[base * 128 + n4 + i]))));
#pragma unroll
      for (int it = 0; it < 16; ++it) {
        int k = it * 16 + kk * 2;
        float4 v0 = *(const float4*)(W + k * 128 + n4);
        float4 v1 = *(const float4*)(W + (k + 1) * 128 + n4);
        int pk = (k >> 5) * 512 + ((k >> 3) & 3) * 128 + (k & 7);
        const float* e0 = (const float*)&v0;
        const float* e1 = (const float*)&v1;
#pragma unroll
        for (int i = 0; i < 4; ++i) {
          int n = n4 + i;
          int pos_ = (n >> 4) * 4096 + pk + (n & 15) * 8;
          *(unsigned*)&tile[pos_] =
              (unsigned)f2bf(e0[i] * te4[i]) | ((unsigned)f2bf(e1[i] * te4[i]) << 16);
        }
      }
      __syncthreads();
      ushort_t* dst = w2P + s * 32768;
#pragma unroll
      for (int it = 0; it < 16; ++it)
        *(uint4*)(dst + (it * 256 + t) * 8) = *(const uint4*)(tile + (it * 256 + t) * 8);
    }
    return;
  }
  if (bx < 24) {
    int s = bx - 16, n = t;
    int base = (s >> 1) * 8 + wsI[s];
    float a = b1[base * 256 + n];
#pragma unroll 16
    for (int k = 0; k < 128; ++k)
      a += ln_b[base * 128 + k] * w1[(base * 128 + k) * 256 + n];
    wsP[s * 384 + n] = a;
    if (n < 128) {
      float te = tf[n] * (1.0f / (1.0f + __expf(-gate[base * 128 + n])));
      wsP[s * 384 + 256 + n] = 0.5f * (1.0f + te) * b2[base * 128 + n];
    }
    return;
  }
  int gid = (bx - 24) * 256 + t;
  if (gid < 4096) {
    int j = gid & 7, ln = (gid >> 3) & 63, nt = gid >> 9;
    int k = (ln >> 4) * 8 + j, n = nt * 16 + (ln & 15);
    pwP[gid] = f2bf(proj_w[k * 128 + n]);
  } else if (gid < 4224) {
    int d = gid - 4096;
    pb[d] = proj_b[d] + pos[d];
  }
}

// ---------------------------------------------------------------------------
// Kernel B (r5, verified 243.5us): 4096 blocks x 256 thr (4 waves), 32
// rows/block, 4 blocks/CU (LDS 34.3KB). mm1 SWAPPED (z1^T = mfma(w1frag,
// hnfrag)) -> gelu scatter = 8 conflict-free ds_write_b64/wave. Stage
// barriers lgkm-only (weight prefetch loads span barriers); setprio around
// MFMA clusters. Frag groups (16): g = rt*8 + kb, element (kq,m,j) at
// g*544 + kq*136 + m*8 + j  (hn uses kb 0..3; z1 uses kb 0..7, phase-union).
// ---------------------------------------------------------------------------
__global__ __launch_bounds__(256, 4) void uv6_main(
    const float* __restrict__ x, const float* __restrict__ cls_w,
    const float* __restrict__ cls_b, const float* __restrict__ wsP,
    const float* __restrict__ pb, const ushort_t* __restrict__ pwP,
    const ushort_t* __restrict__ w1P, const ushort_t* __restrict__ w2P,
    float* __restrict__ out) {
  __shared__ float hbuf[TBROWS * HSTR];      // 16896 B
  __shared__ ushort_t frag[16 * FGSTR];      // 17408 B (x/hn/z1 phase-unioned)

  const int tid = threadIdx.x;
  const int w = tid >> 6, lane = tid & 63, q = lane >> 4, m0 = lane & 15;
  const int r = tid >> 3, p = tid & 7;       // LN/logits row (0..31) / col-part
  const int rt_r = r >> 4, m_r = r & 15;
  const long rowbase = (long)blockIdx.x * TBROWS;
  ushort_t* fb = &frag[q * FQSTR + m0 * 8];  // per-lane frag base (mm reads)

  // ---- phase 0: x tile [32 x 32] -> A-fragments (bf16) ----
  {
    float4 xv = *(const float4*)(x + (rowbase + r) * 32 + p * 4);
    unsigned u01 = f2bf2(xv.x, xv.y), u23 = f2bf2(xv.z, xv.w);
    ushort_t* dst = &frag[(rt_r * 8) * FGSTR + (p >> 1) * FQSTR + m_r * 8 + (p & 1) * 4];
    *(unsigned*)dst = u01;
    *(unsigned*)(dst + 2) = u23;
  }
  __syncthreads();

  // ---- projection: h = x @ proj_w + (proj_b+pos) ; wave w owns nt {2w,2w+1}
  {
    s16x8 bp0 = *(const s16x8*)(pwP + ((2 * w + 0) * 64 + lane) * 8);
    s16x8 bp1 = *(const s16x8*)(pwP + ((2 * w + 1) * 64 + lane) * 8);
    float bv0 = pb[(2 * w + 0) * 16 + m0];
    float bv1 = pb[(2 * w + 1) * 16 + m0];
    f32x4 acc[2][2];
#pragma unroll
    for (int rt = 0; rt < 2; ++rt) {
      acc[rt][0] = (f32x4){bv0, bv0, bv0, bv0};
      acc[rt][1] = (f32x4){bv1, bv1, bv1, bv1};
    }
#pragma unroll
    for (int rt = 0; rt < 2; ++rt) {
      s16x8 af = *(const s16x8*)&fb[(rt * 8) * FGSTR];
      acc[rt][0] = __builtin_amdgcn_mfma_f32_16x16x32_bf16(af, bp0, acc[rt][0], 0, 0, 0);
      acc[rt][1] = __builtin_amdgcn_mfma_f32_16x16x32_bf16(af, bp1, acc[rt][1], 0, 0, 0);
    }
#pragma unroll
    for (int rt = 0; rt < 2; ++rt)
#pragma unroll
      for (int ni = 0; ni < 2; ++ni) {
        int col = (2 * w + ni) * 16 + m0;
#pragma unroll
        for (int reg = 0; reg < 4; ++reg)
          hbuf[(rt * 16 + 4 * q + reg) * HSTR + col] = acc[rt][ni][reg];
      }
  }
  __syncthreads();

  float* outH = out + (size_t)BATCH * 2;

  // ---- 8 FFN block stages ----
  for (int s = 0; s < 8; ++s) {
    const float* c1 = wsP + s * 384;
    const float* c2 = c1 + 256;
    const ushort_t* w1s = w1P + s * 32768;
    const ushort_t* w2s = w2P + s * 32768;

    // ---- prefetch mm1 A-frags (hidden behind LN): n-tiles 4w..4w+3 ----
    s16x8 bfr1[4][4];
#pragma unroll
    for (int ni = 0; ni < 4; ++ni)
#pragma unroll
      for (int ks = 0; ks < 4; ++ks)
        bfr1[ni][ks] = *(const s16x8*)(w1s + (((4 * w + ni) * 4 + ks) * 64 + lane) * 8);

    // -- LayerNorm (folded: hn = (h-mu)*rstd) + pack into frag layout --
    {
      const float* hr = hbuf + r * HSTR + p * 16;
      float hv[16];
#pragma unroll
      for (int i = 0; i < 4; ++i)
        *(float4*)(hv + i * 4) = *(const float4*)(hr + i * 4);
      float sum = 0.0f, ssq = 0.0f;
#pragma unroll
      for (int i = 0; i < 16; ++i) { sum += hv[i]; ssq += hv[i] * hv[i]; }
      sum += dpp_xor1(sum); ssq += dpp_xor1(ssq);
      sum += dpp_xor2(sum); ssq += dpp_xor2(ssq);
      sum += __shfl_xor(sum, 4); ssq += __shfl_xor(ssq, 4);
      float mu = sum * (1.0f / 128.0f);
      float rstd = rsqrtf(ssq * (1.0f / 128.0f) - mu * mu + 1e-5f);
      float nmu = -mu * rstd;
#pragma unroll
      for (int g = 0; g < 2; ++g) {
        union { unsigned u[4]; s16x8 v; } tv;
#pragma unroll
        for (int jj = 0; jj < 4; ++jj) {
          float a = fmaf(hv[g * 8 + jj * 2], rstd, nmu);
          float b = fmaf(hv[g * 8 + jj * 2 + 1], rstd, nmu);
          tv.u[jj] = f2bf2(a, b);
        }
        // col c = 16p + 8g + j  ->  kb = p>>1, k-quad = (p&1)*2 + g
        int kb = p >> 1, kq = (p & 1) * 2 + g;
        *(s16x8*)&frag[(rt_r * 8 + kb) * FGSTR + kq * FQSTR + m_r * 8] = tv.v;
      }
    }
    BARRIER_LDS();   // barrier A: hn frags ready

    // -- matmul1 (SWAPPED): z1^T = w1'^T @ hn^T, wave w owns nt {4w..4w+3} --
    f32x4 a1[2][4];
#pragma unroll
    for (int ni = 0; ni < 4; ++ni) {
      f32x4 bv = *(const f32x4*)&c1[(4 * w + ni) * 16 + 4 * q];
#pragma unroll
      for (int rt = 0; rt < 2; ++rt) a1[rt][ni] = bv;
    }
    __builtin_amdgcn_s_setprio(1);
#pragma unroll
    for (int ks = 0; ks < 4; ++ks) {
      s16x8 hf[2];
#pragma unroll
      for (int rt = 0; rt < 2; ++rt)
        hf[rt] = *(const s16x8*)&fb[(rt * 8 + ks) * FGSTR];
#pragma unroll
      for (int rt = 0; rt < 2; ++rt)
#pragma unroll
        for (int ni = 0; ni < 4; ++ni)
          a1[rt][ni] = __builtin_amdgcn_mfma_f32_16x16x32_bf16(bfr1[ni][ks], hf[rt], a1[rt][ni], 0, 0, 0);
    }
    __builtin_amdgcn_s_setprio(0);
    BARRIER_LDS();   // barrier M: all waves done reading hn frags

    // ---- prefetch mm2 B-frags + c2 (hidden behind gelu/scatter) ----
    s16x8 bfr2[2][8];
#pragma unroll
    for (int ni = 0; ni < 2; ++ni)
#pragma unroll
      for (int ks = 0; ks < 8; ++ks)
        bfr2[ni][ks] = *(const s16x8*)(w2s + (((2 * w + ni) * 8 + ks) * 64 + lane) * 8);
    float cv0 = c2[(2 * w + 0) * 16 + m0];
    float cv1 = c2[(2 * w + 1) * 16 + m0];

    // -- gelu + pack z1^T into mm2 A-frag layout: 8 x ds_write_b64 --
    // n = (4w+ni)*16 + 4q + reg -> kb = 2w+(ni>>1), kq = (2ni+(q>>1))&3,
    // j = 4(q&1)+reg  (4 consecutive j per lane -> one b64)
    {
      int j0 = 4 * (q & 1), kqb = q >> 1;
#pragma unroll
      for (int ni = 0; ni < 4; ++ni) {
        int kb = 2 * w + (ni >> 1);
        int kq = (2 * ni + kqb) & 3;
#pragma unroll
        for (int rt = 0; rt < 2; ++rt) {
          unsigned lo = f2bf2(geluf(a1[rt][ni][0]), geluf(a1[rt][ni][1]));
          unsigned hi = f2bf2(geluf(a1[rt][ni][2]), geluf(a1[rt][ni][3]));
          *(u32x2*)&frag[(rt * 8 + kb) * FGSTR + kq * FQSTR + m0 * 8 + j0] =
              (u32x2){lo, hi};
        }
      }
    }
    BARRIER_LDS();   // barrier B: z1 frags ready

    // -- matmul2: z2' = z1 @ w2' + c2' (wave w owns nt2 {2w, 2w+1}) --
    f32x4 a2[2][2];
#pragma unroll
    for (int rt = 0; rt < 2; ++rt) {
      a2[rt][0] = (f32x4){cv0, cv0, cv0, cv0};
      a2[rt][1] = (f32x4){cv1, cv1, cv1, cv1};
    }
    __builtin_amdgcn_s_setprio(1);
#pragma unroll
    for (int kb = 0; kb < 8; ++kb) {
      s16x8 af[2];
#pragma unroll
      for (int rt = 0; rt < 2; ++rt)
        af[rt] = *(const s16x8*)&fb[(rt * 8 + kb) * FGSTR];
#pragma unroll
      for (int rt = 0; rt < 2; ++rt) {
        a2[rt][0] = __builtin_amdgcn_mfma_f32_16x16x32_bf16(af[rt], bfr2[0][kb], a2[rt][0], 0, 0, 0);
        a2[rt][1] = __builtin_amdgcn_mfma_f32_16x16x32_bf16(af[rt], bfr2[1][kb], a2[rt][1], 0, 0, 0);
      }
    }
    __builtin_amdgcn_s_setprio(0);

    // -- epilogue: h += z2' (scaling folded into w2'/c2') --
#pragma unroll
    for (int rt = 0; rt < 2; ++rt)
#pragma unroll
      for (int ni = 0; ni < 2; ++ni) {
        int col = (2 * w + ni) * 16 + m0;
#pragma unroll
        for (int reg = 0; reg < 4; ++reg)
          hbuf[(rt * 16 + 4 * q + reg) * HSTR + col] += a2[rt][ni][reg];
      }
    BARRIER_LDS();   // barrier C: h complete for next LN
  }

  // ---- h write-out: flat, lane-contiguous float4 (coalesced) ----
#pragma unroll
  for (int it = 0; it < 4; ++it) {
    int p4 = it * 256 + tid;
    int row = p4 >> 5, c = (p4 & 31) * 4;
    float4 o = *(const float4*)(hbuf + row * HSTR + c);
    *(float4*)(outH + rowbase * 128 + p4 * 4) = o;
  }

  // ---- logits = h @ cls_w + cls_b (8 lanes/row, DPP+shfl reduce) ----
  {
    const float* hr = hbuf + r * HSTR + p * 16;
    float l0 = 0.0f, l1 = 0.0f;
#pragma unroll
    for (int i = 0; i < 16; i += 4) {
      float4 v = *(const float4*)(hr + i);
      int c = (p * 16 + i) * 2;
      l0 += v.x * cls_w[c] + v.y * cls_w[c + 2] + v.z * cls_w[c + 4] + v.w * cls_w[c + 6];
      l1 += v.x * cls_w[c + 1] + v.y * cls_w[c + 3] + v.z * cls_w[c + 5] + v.w * cls_w[c + 7];
    }
    l0 += dpp_xor1(l0); l1 += dpp_xor1(l1);
    l0 += dpp_xor2(l0); l1 += dpp_xor2(l1);
    l0 += __shfl_xor(l0, 4); l1 += __shfl_xor(l1, 4);
    if (p == 0) {
      float2 lg = {l0 + cls_b[0], l1 + cls_b[1]};
      *(float2*)(out + (rowbase + r) * 2) = lg;
    }
  }
}

// ---------------------------------------------------------------------------
extern "C" void kernel_launch(void* const* d_in, const int* in_sizes, int n_in,
                              void* d_out, int out_size, void* d_ws, size_t ws_size,
                              hipStream_t stream) {
  (void)in_sizes; (void)n_in; (void)out_size; (void)ws_size;
  const float* x      = (const float*)d_in[0];
  const float* proj_w = (const float*)d_in[1];
  const float* proj_b = (const float*)d_in[2];
  const float* pos    = (const float*)d_in[3];
  const float* sel_w  = (const float*)d_in[4];
  const float* sel_b  = (const float*)d_in[5];
  const float* ln_s   = (const float*)d_in[6];
  const float* ln_b   = (const float*)d_in[7];
  const float* w1     = (const float*)d_in[8];
  const float* b1     = (const float*)d_in[9];
  const float* w2     = (const float*)d_in[10];
  const float* b2     = (const float*)d_in[11];
  const float* gate   = (const float*)d_in[12];
  const float* cls_w  = (const float*)d_in[13];
  const float* cls_b  = (const float*)d_in[14];
  const float* tf     = (const float*)d_in[15];

  char* ws = (char*)d_ws;
  int* wsI        = (int*)(ws + WS_IDX);
  float* wsP      = (float*)(ws + WS_PRM);
  float* pb       = (float*)(ws + WS_PB);
  ushort_t* pwP   = (ushort_t*)(ws + WS_PW);
  ushort_t* w1P   = (ushort_t*)(ws + WS_W1);
  ushort_t* w2P   = (ushort_t*)(ws + WS_W2);
  float* dump     = (float*)(ws + WS_DMP);
  float* outF     = (float*)d_out;

  uv6_warm<<<512, 256, 0, stream>>>(w1, w2, dump);
  uv6_select<<<1, 1024, 0, stream>>>(x, proj_w, proj_b, pos, sel_w, sel_b, ln_s,
                                     ln_b, w1, b1, w2, b2, gate, tf, wsI);
  uv6_pack<<<41, 256, 0, stream>>>(w1, w2, ln_s, ln_b, b1, b2, gate, tf,
                                   proj_w, proj_b, pos, wsI, w1P, w2P, wsP,
                                   pwP, pb);
  uv6_main<<<BATCH / TBROWS, 256, 0, stream>>>(x, cls_w, cls_b, wsP, pb, pwP,
                                               w1P, w2P, outF);
}